// Round 6
// baseline (1004.181 us; speedup 1.0000x reference)
//
#include <hip/hip_runtime.h>
#include <hip/hip_fp16.h>

#define NPTS 400000
#define MVOX 300000
#define KK 27
#define KD 8
#define CIN 4
#define C0 32
#define NCLS 19
#define EPS 1e-5f
#define NTILE (MVOX / 16)          // 18750
#define GS1 ((MVOX + 255) / 256)   // 1172 conv_s1 blocks
#define GT ((NTILE + 3) / 4)       // 4688 conv32 blocks

typedef __attribute__((ext_vector_type(8))) _Float16 half8;
typedef __attribute__((ext_vector_type(4))) float f32x4;

// ---- fp16 pack/unpack helpers ----
__device__ __forceinline__ uint32_t pack2(float a, float b) {
    __half2 h = __floats2half2_rn(a, b);
    return __builtin_bit_cast(uint32_t, h);
}
__device__ __forceinline__ float2 unpack2(uint32_t u) {
    return __half22float2(__builtin_bit_cast(__half2, u));
}
__device__ __forceinline__ void unpack8(uint4 u, float* f) {
    float2 a = unpack2(u.x), b = unpack2(u.y), c = unpack2(u.z), d = unpack2(u.w);
    f[0] = a.x; f[1] = a.y; f[2] = b.x; f[3] = b.y;
    f[4] = c.x; f[5] = c.y; f[6] = d.x; f[7] = d.y;
}
__device__ __forceinline__ uint4 pack8(const float* f) {
    return make_uint4(pack2(f[0], f[1]), pack2(f[2], f[3]),
                      pack2(f[4], f[5]), pack2(f[6], f[7]));
}

// ---------------- voxelization ----------------
__global__ void vox_accum(const float* __restrict__ pf, const int* __restrict__ iq,
                          float* __restrict__ counts, float* __restrict__ vox) {
    int i = blockIdx.x * blockDim.x + threadIdx.x;
    if (i >= NPTS) return;
    int q = iq[i];
    float4 f = *reinterpret_cast<const float4*>(pf + (size_t)i * CIN);
    atomicAdd(&counts[q], 1.0f);
    atomicAdd(&vox[q * CIN + 0], f.x);
    atomicAdd(&vox[q * CIN + 1], f.y);
    atomicAdd(&vox[q * CIN + 2], f.z);
    atomicAdd(&vox[q * CIN + 3], f.w);
}

__global__ void vox_div_h(const float4* __restrict__ vox, const float* __restrict__ counts,
                          uint2* __restrict__ voxh) {
    int i = blockIdx.x * blockDim.x + threadIdx.x;
    if (i >= MVOX) return;
    float inv = 1.0f / fmaxf(counts[i], 1.0f);
    float4 v = vox[i];
    voxh[i] = make_uint2(pack2(v.x * inv, v.y * inv), pack2(v.z * inv, v.w * inv));
}

// ------------- W prep: [k][ci][co] fp32 -> per-lane B-fragment fp16 -------------
__global__ void wprep(const float* __restrict__ W0, const float* __restrict__ W1,
                      const float* __restrict__ W2, uint4* __restrict__ Wf) {
    int t = blockIdx.x * blockDim.x + threadIdx.x;
    if (t >= 3 * KK * 128) return;
    int layer = t / (KK * 128);
    int rem = t % (KK * 128);
    int k = rem / 128;
    int h = (rem >> 6) & 1;
    int lane = rem & 63;
    const float* W = (layer == 0) ? W0 : (layer == 1) ? W1 : W2;
    const float* wk = W + k * (C0 * C0);
    int co = h * 16 + (lane & 15);
    int ci0 = (lane >> 4) * 8;
    float f[8];
#pragma unroll
    for (int j = 0; j < 8; j++) f[j] = wk[(ci0 + j) * C0 + co];
    Wf[t] = pack8(f);
}

// ------- conv layer 1 (4 -> 32), fp16 in/out, fused block BN partials -------
__global__ __launch_bounds__(256) void conv_s1_h(const uint2* __restrict__ x,
                                                 const int* __restrict__ nbrs,
                                                 const float* __restrict__ W,
                                                 uint4* __restrict__ out,
                                                 float* __restrict__ partials) {
    int i = blockIdx.x * blockDim.x + threadIdx.x;
    const bool active = i < MVOX;
    float acc[C0];
#pragma unroll
    for (int c = 0; c < C0; c++) acc[c] = 0.f;
    if (active) {
        const int* nb = nbrs + (size_t)i * KK;
#pragma unroll
        for (int k = 0; k < KK; k++) {
            int idx = nb[k];
            float m = (idx >= 0) ? 1.f : 0.f;
            uint2 r = x[idx < 0 ? 0 : idx];
            float2 ab = unpack2(r.x), cd = unpack2(r.y);
            float xs[4] = {m * ab.x, m * ab.y, m * cd.x, m * cd.y};
            const float* wk = W + k * (CIN * C0);   // k uniform -> scalar loads
#pragma unroll
            for (int j = 0; j < 4; j++) {
#pragma unroll
                for (int co = 0; co < C0; co++) acc[co] += xs[j] * wk[j * C0 + co];
            }
        }
        uint4* o = out + (size_t)i * 4;
#pragma unroll
        for (int p = 0; p < 4; p++) o[p] = pack8(acc + p * 8);
    }
    // fused BN partials: wave shuffle reduce (totals land in lane 0)
    float q[C0];
#pragma unroll
    for (int c = 0; c < C0; c++) q[c] = acc[c] * acc[c];
#pragma unroll
    for (int off = 32; off >= 1; off >>= 1) {
#pragma unroll
        for (int c = 0; c < C0; c++) {
            acc[c] += __shfl_down(acc[c], off);
            q[c] += __shfl_down(q[c], off);
        }
    }
    __shared__ float ls[4][64];
    const int wid = threadIdx.x >> 6, lane = threadIdx.x & 63;
    if (lane == 0) {
#pragma unroll
        for (int c = 0; c < C0; c++) { ls[wid][c] = acc[c]; ls[wid][C0 + c] = q[c]; }
    }
    __syncthreads();
    if (threadIdx.x < 64)
        partials[(size_t)blockIdx.x * 64 + threadIdx.x] =
            ls[0][threadIdx.x] + ls[1][threadIdx.x] + ls[2][threadIdx.x] + ls[3][threadIdx.x];
}

// --- conv 32->32 via MFMA, BN(prev)+ReLU fused into gather, fused BN partials ---
__global__ __launch_bounds__(256) void conv32_mfma(const uint4* __restrict__ x,
                                                   const int* __restrict__ nbrs,
                                                   const uint4* __restrict__ Wf,
                                                   const float* __restrict__ ss,
                                                   __half* __restrict__ out,
                                                   float* __restrict__ partials) {
    const int lane = threadIdx.x & 63;
    const int wid = threadIdx.x >> 6;
    const int tile = blockIdx.x * 4 + wid;
    const bool active = tile < NTILE;
    const int row = lane & 15;
    const int chunk = lane >> 4;
    const int col = lane & 15;
    float sc[8], sh[8];
#pragma unroll
    for (int j = 0; j < 8; j++) {
        sc[j] = ss[chunk * 8 + j];
        sh[j] = ss[C0 + chunk * 8 + j];
    }
    f32x4 acc0 = {0.f, 0.f, 0.f, 0.f}, acc1 = {0.f, 0.f, 0.f, 0.f};
    if (active) {
        const int vr = tile * 16 + row;
        const int* nb = nbrs + (size_t)vr * KK;
#pragma unroll
        for (int k = 0; k < KK; k++) {
            int idx = nb[k];
            float m = (idx >= 0) ? 1.f : 0.f;
            uint4 ar = x[(size_t)(idx < 0 ? 0 : idx) * 4 + chunk];
            float f[8], g[8];
            unpack8(ar, f);
#pragma unroll
            for (int j = 0; j < 8; j++) g[j] = m * fmaxf(f[j] * sc[j] + sh[j], 0.f);
            half8 a = __builtin_bit_cast(half8, pack8(g));
            half8 b0 = __builtin_bit_cast(half8, Wf[k * 128 + lane]);
            half8 b1 = __builtin_bit_cast(half8, Wf[k * 128 + 64 + lane]);
            acc0 = __builtin_amdgcn_mfma_f32_16x16x32_f16(a, b0, acc0, 0, 0, 0);
            acc1 = __builtin_amdgcn_mfma_f32_16x16x32_f16(a, b1, acc1, 0, 0, 0);
        }
        // D layout: col = lane&15, row = chunk*4 + reg
        __half* obase = out + (size_t)tile * 16 * C0;
#pragma unroll
        for (int r = 0; r < 4; r++) {
            int orow = chunk * 4 + r;
            obase[orow * C0 + col] = __float2half(acc0[r]);
            obase[orow * C0 + 16 + col] = __float2half(acc1[r]);
        }
    }
    // fused BN partials: acc0 holds channel col, acc1 channel col+16
    float s0 = 0.f, q0 = 0.f, s1 = 0.f, q1 = 0.f;
#pragma unroll
    for (int r = 0; r < 4; r++) {
        s0 += acc0[r]; q0 += acc0[r] * acc0[r];
        s1 += acc1[r]; q1 += acc1[r] * acc1[r];
    }
    s0 += __shfl_xor(s0, 16); q0 += __shfl_xor(q0, 16);
    s1 += __shfl_xor(s1, 16); q1 += __shfl_xor(q1, 16);
    s0 += __shfl_xor(s0, 32); q0 += __shfl_xor(q0, 32);
    s1 += __shfl_xor(s1, 32); q1 += __shfl_xor(q1, 32);
    __shared__ float ls[4][64];
    if (lane < 16) {
        ls[wid][col] = s0;
        ls[wid][16 + col] = s1;
        ls[wid][32 + col] = q0;
        ls[wid][48 + col] = q1;
    }
    __syncthreads();
    if (threadIdx.x < 64)
        partials[(size_t)blockIdx.x * 64 + threadIdx.x] =
            ls[0][threadIdx.x] + ls[1][threadIdx.x] + ls[2][threadIdx.x] + ls[3][threadIdx.x];
}

// ------------- BN: reduce per-block partials + finalize scale/shift -------------
__global__ __launch_bounds__(1024) void bn_reduce_fin(const float* __restrict__ partials,
                                                      int nblocks,
                                                      const float* __restrict__ g,
                                                      const float* __restrict__ b,
                                                      float* __restrict__ ss) {
    const int tid = threadIdx.x;
    const int c = tid & 63;
    const int part = tid >> 6;               // 0..15
    float acc = 0.f;
    for (int bk = part; bk < nblocks; bk += 16) acc += partials[(size_t)bk * 64 + c];
    __shared__ float ls[16][64];
    ls[part][c] = acc;
    __syncthreads();
    __shared__ float fin[64];
    if (tid < 64) {
        float t = 0.f;
#pragma unroll
        for (int p = 0; p < 16; p++) t += ls[p][tid];
        fin[tid] = t;
    }
    __syncthreads();
    if (tid < C0) {
        float mean = fin[tid] * (1.0f / (float)MVOX);
        float var = fin[C0 + tid] * (1.0f / (float)MVOX) - mean * mean;
        float scv = g[tid] * rsqrtf(var + EPS);
        ss[tid] = scv;
        ss[C0 + tid] = b[tid] - mean * scv;
    }
}

// ---- classify_pre: HC[v] = relu(bn_r2(D) + relu(bn_s2(B))) @ Wc   (fp16, 64B rows) ----
__global__ __launch_bounds__(256) void classify_pre(const uint4* __restrict__ D,
                                                    const uint4* __restrict__ B,
                                                    const float* __restrict__ ss_r2,
                                                    const float* __restrict__ ss_s2,
                                                    const float* __restrict__ Wc,
                                                    uint4* __restrict__ HC) {
    int v = blockIdx.x * blockDim.x + threadIdx.x;
    if (v >= MVOX) return;
    float f[C0], h[C0];
#pragma unroll
    for (int p = 0; p < 4; p++) {
        float tf[8], th[8];
        unpack8(D[(size_t)v * 4 + p], tf);
        unpack8(B[(size_t)v * 4 + p], th);
#pragma unroll
        for (int j = 0; j < 8; j++) { f[p * 8 + j] = tf[j]; h[p * 8 + j] = th[j]; }
    }
    float hh[C0];
#pragma unroll
    for (int j = 0; j < C0; j++) {
        float skip = fmaxf(h[j] * ss_s2[j] + ss_s2[C0 + j], 0.f);
        hh[j] = fmaxf(f[j] * ss_r2[j] + ss_r2[C0 + j] + skip, 0.f);
    }
    float o[20];
#pragma unroll
    for (int c = 0; c < 20; c++) o[c] = 0.f;
#pragma unroll
    for (int ci = 0; ci < C0; ci++) {
        float xv = hh[ci];
#pragma unroll
        for (int c = 0; c < NCLS; c++) o[c] += xv * Wc[ci * NCLS + c];
    }
    uint4* dst = HC + (size_t)v * 4;
    dst[0] = pack8(o);
    dst[1] = pack8(o + 8);
    *reinterpret_cast<uint2*>(dst + 2) = make_uint2(pack2(o[16], o[17]), pack2(o[18], 0.f));
}

// ---------------- devoxelize: out[i] = sum_k w * HC[idx] + bc ----------------
__global__ __launch_bounds__(256) void devox_out(const uint4* __restrict__ HC,
                                                 const int4* __restrict__ idxd,
                                                 const float4* __restrict__ wdev,
                                                 const float* __restrict__ bc,
                                                 float* __restrict__ out) {
    int i = blockIdx.x * blockDim.x + threadIdx.x;
    if (i >= NPTS) return;
    int4 i0 = idxd[2 * i], i1 = idxd[2 * i + 1];
    float4 w0 = wdev[2 * i], w1 = wdev[2 * i + 1];
    int idxs[8] = {i0.x, i0.y, i0.z, i0.w, i1.x, i1.y, i1.z, i1.w};
    float wsv[8] = {w0.x, w0.y, w0.z, w0.w, w1.x, w1.y, w1.z, w1.w};
    float acc[20];
#pragma unroll
    for (int c = 0; c < 20; c++) acc[c] = 0.f;
#pragma unroll
    for (int k = 0; k < KD; k++) {
        float m = (idxs[k] >= 0) ? wsv[k] : 0.f;
        const uint4* hr = HC + (size_t)(idxs[k] < 0 ? 0 : idxs[k]) * 4;
        uint4 a = hr[0], b2 = hr[1];
        uint2 cp = *reinterpret_cast<const uint2*>(hr + 2);
        float fa[8], fb[8];
        unpack8(a, fa); unpack8(b2, fb);
#pragma unroll
        for (int j = 0; j < 8; j++) { acc[j] += m * fa[j]; acc[8 + j] += m * fb[j]; }
        float2 t0 = unpack2(cp.x), t1 = unpack2(cp.y);
        acc[16] += m * t0.x; acc[17] += m * t0.y; acc[18] += m * t1.x;
    }
    float* op = out + (size_t)i * NCLS;
#pragma unroll
    for (int c = 0; c < NCLS; c++) op[c] = acc[c] + bc[c];
}

extern "C" void kernel_launch(void* const* d_in, const int* in_sizes, int n_in,
                              void* d_out, int out_size, void* d_ws, size_t ws_size,
                              hipStream_t stream) {
    const float* point_fea = (const float*)d_in[0];
    const int*   idx_query = (const int*)d_in[1];
    const int*   nbrs      = (const int*)d_in[2];
    const int*   idx_dev   = (const int*)d_in[3];
    const float* w_dev     = (const float*)d_in[4];
    const float* W_s1      = (const float*)d_in[5];
    const float* W_s2      = (const float*)d_in[6];
    const float* g_s1      = (const float*)d_in[7];
    const float* b_s1      = (const float*)d_in[8];
    const float* g_s2      = (const float*)d_in[9];
    const float* b_s2      = (const float*)d_in[10];
    const float* W_r1      = (const float*)d_in[11];
    const float* W_r2      = (const float*)d_in[12];
    const float* g_r1      = (const float*)d_in[13];
    const float* b_r1      = (const float*)d_in[14];
    const float* g_r2      = (const float*)d_in[15];
    const float* b_r2      = (const float*)d_in[16];
    const float* W_c       = (const float*)d_in[17];
    const float* b_c       = (const float*)d_in[18];
    float* out = (float*)d_out;

    float* ws = (float*)d_ws;
    const size_t M = MVOX;
    float* ss       = ws;                      // 256
    float* partials = ws + 256;                // GT*64 = 300032 floats
    float* counts   = partials + (size_t)GT * 64;   // M   [memset from here]
    float* vox32    = counts + M;              // 4M fp32
    uint2* voxh     = (uint2*)(vox32 + 4 * M); // M * 8B
    uint4* Wf       = (uint4*)((float*)voxh + 2 * M);  // 3*27*128 uint4
    float* bufs     = (float*)Wf + (size_t)3 * KK * 128 * 4;
    uint4* A = (uint4*)bufs;                   // raw conv_s1 out; later reused for HC
    uint4* B = A + M * 4;                      // raw conv_s2 out
    uint4* C = B + M * 4;                      // raw conv_r1 out
    uint4* D = C + M * 4;                      // raw conv_r2 out

    // zero only the atomically-accumulated regions: counts(M)+vox(4M)
    hipMemsetAsync(counts, 0, (size_t)(5 * M) * sizeof(float), stream);

    dim3 blk(256);
    dim3 gN((NPTS + 255) / 256);
    dim3 gM(GS1);
    dim3 gT(GT);
    dim3 gW((3 * KK * 128 + 255) / 256);

    vox_accum<<<gN, blk, 0, stream>>>(point_fea, idx_query, counts, vox32);
    vox_div_h<<<gM, blk, 0, stream>>>((const float4*)vox32, counts, voxh);
    wprep<<<gW, blk, 0, stream>>>(W_s2, W_r1, W_r2, Wf);

    conv_s1_h<<<gM, blk, 0, stream>>>(voxh, nbrs, W_s1, A, partials);
    bn_reduce_fin<<<1, 1024, 0, stream>>>(partials, GS1, g_s1, b_s1, ss + 0);

    conv32_mfma<<<gT, blk, 0, stream>>>(A, nbrs, Wf + 0 * KK * 128, ss + 0, (__half*)B, partials);
    bn_reduce_fin<<<1, 1024, 0, stream>>>(partials, GT, g_s2, b_s2, ss + 64);

    conv32_mfma<<<gT, blk, 0, stream>>>(B, nbrs, Wf + 1 * KK * 128, ss + 64, (__half*)C, partials);
    bn_reduce_fin<<<1, 1024, 0, stream>>>(partials, GT, g_r1, b_r1, ss + 128);

    conv32_mfma<<<gT, blk, 0, stream>>>(C, nbrs, Wf + 2 * KK * 128, ss + 128, (__half*)D, partials);
    bn_reduce_fin<<<1, 1024, 0, stream>>>(partials, GT, g_r2, b_r2, ss + 192);

    // HC = relu(bn_r2(D) + relu(bn_s2(B))) @ Wc  -> reuse A's buffer
    classify_pre<<<gM, blk, 0, stream>>>(D, B, ss + 192, ss + 64, W_c, A);

    devox_out<<<gN, blk, 0, stream>>>(A, (const int4*)idx_dev,
                                      (const float4*)w_dev, b_c, out);
}

// Round 7
// 698.193 us; speedup vs baseline: 1.4383x; 1.4383x over previous
//
#include <hip/hip_runtime.h>
#include <hip/hip_fp16.h>

#define NPTS 400000
#define MVOX 300000
#define KK 27
#define KD 8
#define CIN 4
#define C0 32
#define NCLS 19
#define EPS 1e-5f
#define NTILE (MVOX / 16)          // 18750
#define GS1 ((MVOX + 255) / 256)   // 1172 conv_s1 blocks
#define GT ((NTILE + 3) / 4)       // 4688 conv32 blocks
#define NRED 64                    // bn stage-1 reduce blocks

typedef __attribute__((ext_vector_type(8))) _Float16 half8;
typedef __attribute__((ext_vector_type(4))) float f32x4;

// ---- fp16 pack/unpack helpers ----
__device__ __forceinline__ uint32_t pack2(float a, float b) {
    __half2 h = __floats2half2_rn(a, b);
    return __builtin_bit_cast(uint32_t, h);
}
__device__ __forceinline__ float2 unpack2(uint32_t u) {
    return __half22float2(__builtin_bit_cast(__half2, u));
}
__device__ __forceinline__ void unpack8(uint4 u, float* f) {
    float2 a = unpack2(u.x), b = unpack2(u.y), c = unpack2(u.z), d = unpack2(u.w);
    f[0] = a.x; f[1] = a.y; f[2] = b.x; f[3] = b.y;
    f[4] = c.x; f[5] = c.y; f[6] = d.x; f[7] = d.y;
}
__device__ __forceinline__ uint4 pack8(const float* f) {
    return make_uint4(pack2(f[0], f[1]), pack2(f[2], f[3]),
                      pack2(f[4], f[5]), pack2(f[6], f[7]));
}

// ---------------- voxelization ----------------
__global__ void vox_accum(const float* __restrict__ pf, const int* __restrict__ iq,
                          float* __restrict__ counts, float* __restrict__ vox) {
    int i = blockIdx.x * blockDim.x + threadIdx.x;
    if (i >= NPTS) return;
    int q = iq[i];
    float4 f = *reinterpret_cast<const float4*>(pf + (size_t)i * CIN);
    atomicAdd(&counts[q], 1.0f);
    atomicAdd(&vox[q * CIN + 0], f.x);
    atomicAdd(&vox[q * CIN + 1], f.y);
    atomicAdd(&vox[q * CIN + 2], f.z);
    atomicAdd(&vox[q * CIN + 3], f.w);
}

__global__ void vox_div_h(const float4* __restrict__ vox, const float* __restrict__ counts,
                          uint2* __restrict__ voxh) {
    int i = blockIdx.x * blockDim.x + threadIdx.x;
    if (i >= MVOX) return;
    float inv = 1.0f / fmaxf(counts[i], 1.0f);
    float4 v = vox[i];
    voxh[i] = make_uint2(pack2(v.x * inv, v.y * inv), pack2(v.z * inv, v.w * inv));
}

// ------------- W prep: [k][ci][co] fp32 -> per-lane B-fragment fp16 -------------
__global__ void wprep(const float* __restrict__ W0, const float* __restrict__ W1,
                      const float* __restrict__ W2, uint4* __restrict__ Wf) {
    int t = blockIdx.x * blockDim.x + threadIdx.x;
    if (t >= 3 * KK * 128) return;
    int layer = t / (KK * 128);
    int rem = t % (KK * 128);
    int k = rem / 128;
    int h = (rem >> 6) & 1;
    int lane = rem & 63;
    const float* W = (layer == 0) ? W0 : (layer == 1) ? W1 : W2;
    const float* wk = W + k * (C0 * C0);
    int co = h * 16 + (lane & 15);
    int ci0 = (lane >> 4) * 8;
    float f[8];
#pragma unroll
    for (int j = 0; j < 8; j++) f[j] = wk[(ci0 + j) * C0 + co];
    Wf[t] = pack8(f);
}

// ------- conv layer 1 (4 -> 32), fp16 in/out, fused block BN partials -------
__global__ __launch_bounds__(256) void conv_s1_h(const uint2* __restrict__ x,
                                                 const int* __restrict__ nbrs,
                                                 const float* __restrict__ W,
                                                 uint4* __restrict__ out,
                                                 float* __restrict__ partials) {
    int i = blockIdx.x * blockDim.x + threadIdx.x;
    const bool active = i < MVOX;
    float acc[C0];
#pragma unroll
    for (int c = 0; c < C0; c++) acc[c] = 0.f;
    if (active) {
        const int* nb = nbrs + (size_t)i * KK;
#pragma unroll
        for (int k = 0; k < KK; k++) {
            int idx = nb[k];
            float m = (idx >= 0) ? 1.f : 0.f;
            uint2 r = x[idx < 0 ? 0 : idx];
            float2 ab = unpack2(r.x), cd = unpack2(r.y);
            float xs[4] = {m * ab.x, m * ab.y, m * cd.x, m * cd.y};
            const float* wk = W + k * (CIN * C0);   // k uniform -> scalar loads
#pragma unroll
            for (int j = 0; j < 4; j++) {
#pragma unroll
                for (int co = 0; co < C0; co++) acc[co] += xs[j] * wk[j * C0 + co];
            }
        }
        uint4* o = out + (size_t)i * 4;
#pragma unroll
        for (int p = 0; p < 4; p++) o[p] = pack8(acc + p * 8);
    }
    // fused BN partials: wave shuffle reduce (totals land in lane 0)
    float q[C0];
#pragma unroll
    for (int c = 0; c < C0; c++) q[c] = acc[c] * acc[c];
#pragma unroll
    for (int off = 32; off >= 1; off >>= 1) {
#pragma unroll
        for (int c = 0; c < C0; c++) {
            acc[c] += __shfl_down(acc[c], off);
            q[c] += __shfl_down(q[c], off);
        }
    }
    __shared__ float ls[4][64];
    const int wid = threadIdx.x >> 6, lane = threadIdx.x & 63;
    if (lane == 0) {
#pragma unroll
        for (int c = 0; c < C0; c++) { ls[wid][c] = acc[c]; ls[wid][C0 + c] = q[c]; }
    }
    __syncthreads();
    if (threadIdx.x < 64)
        partials[(size_t)blockIdx.x * 64 + threadIdx.x] =
            ls[0][threadIdx.x] + ls[1][threadIdx.x] + ls[2][threadIdx.x] + ls[3][threadIdx.x];
}

// --- conv 32->32 via MFMA, BN(prev)+ReLU fused into gather, fused BN partials ---
__global__ __launch_bounds__(256) void conv32_mfma(const uint4* __restrict__ x,
                                                   const int* __restrict__ nbrs,
                                                   const uint4* __restrict__ Wf,
                                                   const float* __restrict__ ss,
                                                   __half* __restrict__ out,
                                                   float* __restrict__ partials) {
    const int lane = threadIdx.x & 63;
    const int wid = threadIdx.x >> 6;
    const int tile = blockIdx.x * 4 + wid;
    const bool active = tile < NTILE;
    const int row = lane & 15;
    const int chunk = lane >> 4;
    const int col = lane & 15;
    float sc[8], sh[8];
#pragma unroll
    for (int j = 0; j < 8; j++) {
        sc[j] = ss[chunk * 8 + j];
        sh[j] = ss[C0 + chunk * 8 + j];
    }
    f32x4 acc0 = {0.f, 0.f, 0.f, 0.f}, acc1 = {0.f, 0.f, 0.f, 0.f};
    if (active) {
        const int vr = tile * 16 + row;
        const int* nb = nbrs + (size_t)vr * KK;
#pragma unroll
        for (int k = 0; k < KK; k++) {
            int idx = nb[k];
            float m = (idx >= 0) ? 1.f : 0.f;
            uint4 ar = x[(size_t)(idx < 0 ? 0 : idx) * 4 + chunk];
            float f[8], g[8];
            unpack8(ar, f);
#pragma unroll
            for (int j = 0; j < 8; j++) g[j] = m * fmaxf(f[j] * sc[j] + sh[j], 0.f);
            half8 a = __builtin_bit_cast(half8, pack8(g));
            half8 b0 = __builtin_bit_cast(half8, Wf[k * 128 + lane]);
            half8 b1 = __builtin_bit_cast(half8, Wf[k * 128 + 64 + lane]);
            acc0 = __builtin_amdgcn_mfma_f32_16x16x32_f16(a, b0, acc0, 0, 0, 0);
            acc1 = __builtin_amdgcn_mfma_f32_16x16x32_f16(a, b1, acc1, 0, 0, 0);
        }
        // D layout: col = lane&15, row = chunk*4 + reg
        __half* obase = out + (size_t)tile * 16 * C0;
#pragma unroll
        for (int r = 0; r < 4; r++) {
            int orow = chunk * 4 + r;
            obase[orow * C0 + col] = __float2half(acc0[r]);
            obase[orow * C0 + 16 + col] = __float2half(acc1[r]);
        }
    }
    // fused BN partials: acc0 holds channel col, acc1 channel col+16
    float s0 = 0.f, q0 = 0.f, s1 = 0.f, q1 = 0.f;
#pragma unroll
    for (int r = 0; r < 4; r++) {
        s0 += acc0[r]; q0 += acc0[r] * acc0[r];
        s1 += acc1[r]; q1 += acc1[r] * acc1[r];
    }
    s0 += __shfl_xor(s0, 16); q0 += __shfl_xor(q0, 16);
    s1 += __shfl_xor(s1, 16); q1 += __shfl_xor(q1, 16);
    s0 += __shfl_xor(s0, 32); q0 += __shfl_xor(q0, 32);
    s1 += __shfl_xor(s1, 32); q1 += __shfl_xor(q1, 32);
    __shared__ float ls[4][64];
    if (lane < 16) {
        ls[wid][col] = s0;
        ls[wid][16 + col] = s1;
        ls[wid][32 + col] = q0;
        ls[wid][48 + col] = q1;
    }
    __syncthreads();
    if (threadIdx.x < 64)
        partials[(size_t)blockIdx.x * 64 + threadIdx.x] =
            ls[0][threadIdx.x] + ls[1][threadIdx.x] + ls[2][threadIdx.x] + ls[3][threadIdx.x];
}

// ------- BN reduce stage A: 64 blocks, parallel stripe reduce of partials -------
__global__ __launch_bounds__(256) void bn_reduce1(const float* __restrict__ partials,
                                                  int nblocks, float* __restrict__ partial2) {
    const int j = blockIdx.x;                 // 0..NRED-1
    const int tid = threadIdx.x;
    const int c = tid & 63;
    const int sub = tid >> 6;                 // 0..3
    const int per = (nblocks + NRED - 1) / NRED;
    int lo = j * per;
    int hi = lo + per; if (hi > nblocks) hi = nblocks;
    float acc = 0.f;
    for (int bk = lo + sub; bk < hi; bk += 4) acc += partials[(size_t)bk * 64 + c];
    __shared__ float ls[4][64];
    ls[sub][c] = acc;
    __syncthreads();
    if (tid < 64)
        partial2[(size_t)j * 64 + tid] = ls[0][tid] + ls[1][tid] + ls[2][tid] + ls[3][tid];
}

// ------- BN reduce stage B: 1 block, finalize scale/shift -------
__global__ __launch_bounds__(256) void bn_fin(const float* __restrict__ partial2,
                                              const float* __restrict__ g,
                                              const float* __restrict__ b,
                                              float* __restrict__ ss) {
    const int tid = threadIdx.x;
    const int c = tid & 63;
    const int sub = tid >> 6;
    float acc = 0.f;
    for (int bk = sub; bk < NRED; bk += 4) acc += partial2[(size_t)bk * 64 + c];
    __shared__ float ls[4][64];
    ls[sub][c] = acc;
    __syncthreads();
    __shared__ float fin[64];
    if (tid < 64) fin[tid] = ls[0][tid] + ls[1][tid] + ls[2][tid] + ls[3][tid];
    __syncthreads();
    if (tid < C0) {
        float mean = fin[tid] * (1.0f / (float)MVOX);
        float var = fin[C0 + tid] * (1.0f / (float)MVOX) - mean * mean;
        float scv = g[tid] * rsqrtf(var + EPS);
        ss[tid] = scv;
        ss[C0 + tid] = b[tid] - mean * scv;
    }
}

// ---- classify_pre: HC[v] = relu(bn_r2(D) + relu(bn_s2(B))) @ Wc, DENSE 40B rows ----
__global__ __launch_bounds__(256) void classify_pre(const uint4* __restrict__ D,
                                                    const uint4* __restrict__ B,
                                                    const float* __restrict__ ss_r2,
                                                    const float* __restrict__ ss_s2,
                                                    const float* __restrict__ Wc,
                                                    uint2* __restrict__ HC) {
    int v = blockIdx.x * blockDim.x + threadIdx.x;
    if (v >= MVOX) return;
    float f[C0], h[C0];
#pragma unroll
    for (int p = 0; p < 4; p++) {
        float tf[8], th[8];
        unpack8(D[(size_t)v * 4 + p], tf);
        unpack8(B[(size_t)v * 4 + p], th);
#pragma unroll
        for (int j = 0; j < 8; j++) { f[p * 8 + j] = tf[j]; h[p * 8 + j] = th[j]; }
    }
    float hh[C0];
#pragma unroll
    for (int j = 0; j < C0; j++) {
        float skip = fmaxf(h[j] * ss_s2[j] + ss_s2[C0 + j], 0.f);
        hh[j] = fmaxf(f[j] * ss_r2[j] + ss_r2[C0 + j] + skip, 0.f);
    }
    float o[20];
#pragma unroll
    for (int c = 0; c < 20; c++) o[c] = 0.f;
#pragma unroll
    for (int ci = 0; ci < C0; ci++) {
        float xv = hh[ci];
#pragma unroll
        for (int c = 0; c < NCLS; c++) o[c] += xv * Wc[ci * NCLS + c];
    }
    uint2* dst = HC + (size_t)v * 5;
#pragma unroll
    for (int p = 0; p < 5; p++)
        dst[p] = make_uint2(pack2(o[4 * p], o[4 * p + 1]), pack2(o[4 * p + 2], o[4 * p + 3]));
}

// ---------------- devoxelize: out[i] = sum_k w * HC[idx] + bc ----------------
__global__ __launch_bounds__(256) void devox_out(const uint2* __restrict__ HC,
                                                 const int4* __restrict__ idxd,
                                                 const float4* __restrict__ wdev,
                                                 const float* __restrict__ bc,
                                                 float* __restrict__ out) {
    int i = blockIdx.x * blockDim.x + threadIdx.x;
    if (i >= NPTS) return;
    int4 i0 = idxd[2 * i], i1 = idxd[2 * i + 1];
    float4 w0 = wdev[2 * i], w1 = wdev[2 * i + 1];
    int idxs[8] = {i0.x, i0.y, i0.z, i0.w, i1.x, i1.y, i1.z, i1.w};
    float wsv[8] = {w0.x, w0.y, w0.z, w0.w, w1.x, w1.y, w1.z, w1.w};
    float acc[20];
#pragma unroll
    for (int c = 0; c < 20; c++) acc[c] = 0.f;
#pragma unroll
    for (int k = 0; k < KD; k++) {
        float m = (idxs[k] >= 0) ? wsv[k] : 0.f;
        const uint2* hr = HC + (size_t)(idxs[k] < 0 ? 0 : idxs[k]) * 5;
#pragma unroll
        for (int p = 0; p < 5; p++) {
            uint2 u = hr[p];
            float2 t0 = unpack2(u.x), t1 = unpack2(u.y);
            acc[4 * p + 0] += m * t0.x;
            acc[4 * p + 1] += m * t0.y;
            acc[4 * p + 2] += m * t1.x;
            acc[4 * p + 3] += m * t1.y;
        }
    }
    float* op = out + (size_t)i * NCLS;
#pragma unroll
    for (int c = 0; c < NCLS; c++) op[c] = acc[c] + bc[c];
}

extern "C" void kernel_launch(void* const* d_in, const int* in_sizes, int n_in,
                              void* d_out, int out_size, void* d_ws, size_t ws_size,
                              hipStream_t stream) {
    const float* point_fea = (const float*)d_in[0];
    const int*   idx_query = (const int*)d_in[1];
    const int*   nbrs      = (const int*)d_in[2];
    const int*   idx_dev   = (const int*)d_in[3];
    const float* w_dev     = (const float*)d_in[4];
    const float* W_s1      = (const float*)d_in[5];
    const float* W_s2      = (const float*)d_in[6];
    const float* g_s1      = (const float*)d_in[7];
    const float* b_s1      = (const float*)d_in[8];
    const float* g_s2      = (const float*)d_in[9];
    const float* b_s2      = (const float*)d_in[10];
    const float* W_r1      = (const float*)d_in[11];
    const float* W_r2      = (const float*)d_in[12];
    const float* g_r1      = (const float*)d_in[13];
    const float* b_r1      = (const float*)d_in[14];
    const float* g_r2      = (const float*)d_in[15];
    const float* b_r2      = (const float*)d_in[16];
    const float* W_c       = (const float*)d_in[17];
    const float* b_c       = (const float*)d_in[18];
    float* out = (float*)d_out;

    float* ws = (float*)d_ws;
    const size_t M = MVOX;
    float* ss       = ws;                      // 256
    float* partial2 = ws + 256;                // NRED*64 = 4096
    float* partials = partial2 + NRED * 64;    // GT*64
    float* counts   = partials + (size_t)GT * 64;   // M   [memset from here]
    float* vox32    = counts + M;              // 4M fp32
    uint2* voxh     = (uint2*)(vox32 + 4 * M); // M * 8B
    uint4* Wf       = (uint4*)((float*)voxh + 2 * M);  // 3*27*128 uint4
    float* bufs     = (float*)Wf + (size_t)3 * KK * 128 * 4;
    uint4* A = (uint4*)bufs;                   // raw conv_s1 out; later reused for HC
    uint4* B = A + M * 4;                      // raw conv_s2 out
    uint4* C = B + M * 4;                      // raw conv_r1 out
    uint4* D = C + M * 4;                      // raw conv_r2 out

    // zero only the atomically-accumulated regions: counts(M)+vox(4M)
    hipMemsetAsync(counts, 0, (size_t)(5 * M) * sizeof(float), stream);

    dim3 blk(256);
    dim3 gN((NPTS + 255) / 256);
    dim3 gM(GS1);
    dim3 gT(GT);
    dim3 gW((3 * KK * 128 + 255) / 256);

    vox_accum<<<gN, blk, 0, stream>>>(point_fea, idx_query, counts, vox32);
    vox_div_h<<<gM, blk, 0, stream>>>((const float4*)vox32, counts, voxh);
    wprep<<<gW, blk, 0, stream>>>(W_s2, W_r1, W_r2, Wf);

    conv_s1_h<<<gM, blk, 0, stream>>>(voxh, nbrs, W_s1, A, partials);
    bn_reduce1<<<NRED, blk, 0, stream>>>(partials, GS1, partial2);
    bn_fin<<<1, blk, 0, stream>>>(partial2, g_s1, b_s1, ss + 0);

    conv32_mfma<<<gT, blk, 0, stream>>>(A, nbrs, Wf + 0 * KK * 128, ss + 0, (__half*)B, partials);
    bn_reduce1<<<NRED, blk, 0, stream>>>(partials, GT, partial2);
    bn_fin<<<1, blk, 0, stream>>>(partial2, g_s2, b_s2, ss + 64);

    conv32_mfma<<<gT, blk, 0, stream>>>(B, nbrs, Wf + 1 * KK * 128, ss + 64, (__half*)C, partials);
    bn_reduce1<<<NRED, blk, 0, stream>>>(partials, GT, partial2);
    bn_fin<<<1, blk, 0, stream>>>(partial2, g_r1, b_r1, ss + 128);

    conv32_mfma<<<gT, blk, 0, stream>>>(C, nbrs, Wf + 2 * KK * 128, ss + 128, (__half*)D, partials);
    bn_reduce1<<<NRED, blk, 0, stream>>>(partials, GT, partial2);
    bn_fin<<<1, blk, 0, stream>>>(partial2, g_r2, b_r2, ss + 192);

    // HC (dense 40B rows) = relu(bn_r2(D) + relu(bn_s2(B))) @ Wc -> reuse A
    classify_pre<<<gM, blk, 0, stream>>>(D, B, ss + 192, ss + 64, W_c, (uint2*)A);

    devox_out<<<gN, blk, 0, stream>>>((const uint2*)A, (const int4*)idx_dev,
                                      (const float4*)w_dev, b_c, out);
}